// Round 13
// baseline (189.037 us; speedup 1.0000x reference)
//
#include <hip/hip_runtime.h>
#include <hip/hip_bf16.h>
#include <cstdint>

// B=8 T=4 N1=1024 N2=64 DIM=1024 HEADS=8 DHEAD=64 INNER=512
// BT = 32, NR = 1088, concat rows = 34816; A_cat rows 36864 = 144*256 (kv 136 + q 8 tiles)
// Pipeline: {transpose|LN} prep -> qkv8 (256^2, m201 8-phase) -> attention -> out GEMM

typedef __bf16 bf16x8 __attribute__((ext_vector_type(8)));
typedef __bf16 bf16x4 __attribute__((ext_vector_type(4)));
typedef float  f32x4  __attribute__((ext_vector_type(4)));

__device__ __forceinline__ void gload_lds16(const void* g, void* l) {
    __builtin_amdgcn_global_load_lds(
        (const __attribute__((address_space(1))) unsigned int*)g,
        (__attribute__((address_space(3))) unsigned int*)l, 16, 0, 0);
}

// ---------------------------------------------------------------- prep: transpose + LN
__global__ __launch_bounds__(256) void prep_kernel(
    const float* __restrict__ Wq, const float* __restrict__ Wkv,
    const float* __restrict__ Wout,
    __bf16* __restrict__ WqT, __bf16* __restrict__ WkvT, __bf16* __restrict__ WoutT,
    const float* __restrict__ x, const float* __restrict__ lat,
    const float* __restrict__ g_m, const float* __restrict__ b_m,
    const float* __restrict__ g_l, const float* __restrict__ b_l,
    __bf16* __restrict__ concat, __bf16* __restrict__ latln) {
    __shared__ float tile[32][33];
    __shared__ float ss[4], qq[4];
    int id = blockIdx.x;
    if (id < 2048) {
        const float* src; __bf16* dst; int N; int bx, by; float wscale;
        if (id < 512)       { src = Wq;   dst = WqT;   N = 512;
                              bx = id & 15;  by = id >> 4;  wscale = 0.125f; }
        else if (id < 1536) { int i = id - 512;  src = Wkv;  dst = WkvT;  N = 1024;
                              bx = i & 31;  by = i >> 5;  wscale = 1.0f; }
        else                { int i = id - 1536; src = Wout; dst = WoutT; N = 1024;
                              bx = i & 31;  by = i >> 5;  wscale = 1.0f; }
        int K = (id < 1536) ? 1024 : 512;
        int n0 = bx * 32, k0 = by * 32;
        int tx = threadIdx.x & 31, ty = threadIdx.x >> 5;   // 32x8
#pragma unroll
        for (int i = 0; i < 4; ++i)
            tile[ty + i * 8][tx] = src[(size_t)(k0 + ty + i * 8) * N + n0 + tx];
        __syncthreads();
#pragma unroll
        for (int i = 0; i < 4; ++i)
            dst[(size_t)(n0 + ty + i * 8) * K + k0 + tx] =
                (__bf16)(tile[tx][ty + i * 8] * wscale);
        return;
    }
    int row = id - 2048;                // 0..34815
    int bt  = row / 1088;
    int r   = row - bt * 1088;
    const float *src, *g, *b;
    if (r < 1024) { src = x   + ((size_t)(bt * 1024 + r) << 10);        g = g_m; b = b_m; }
    else          { src = lat + ((size_t)(bt * 64 + (r - 1024)) << 10); g = g_l; b = b_l; }
    int t = threadIdx.x;
    float4 v = ((const float4*)src)[t];
    float s = v.x + v.y + v.z + v.w;
    float q = v.x * v.x + v.y * v.y + v.z * v.z + v.w * v.w;
#pragma unroll
    for (int m = 1; m < 64; m <<= 1) { s += __shfl_xor(s, m); q += __shfl_xor(q, m); }
    int w = t >> 6;
    if ((t & 63) == 0) { ss[w] = s; qq[w] = q; }
    __syncthreads();
    s = ss[0] + ss[1] + ss[2] + ss[3];
    q = qq[0] + qq[1] + qq[2] + qq[3];
    float mean = s * (1.0f / 1024.0f);
    float var  = q * (1.0f / 1024.0f) - mean * mean;
    float rstd = rsqrtf(var + 1e-5f);
    float4 gv = ((const float4*)g)[t];
    float4 bv = ((const float4*)b)[t];
    bf16x4 o;
    o[0] = (__bf16)((v.x - mean) * rstd * gv.x + bv.x);
    o[1] = (__bf16)((v.y - mean) * rstd * gv.y + bv.y);
    o[2] = (__bf16)((v.z - mean) * rstd * gv.z + bv.z);
    o[3] = (__bf16)((v.w - mean) * rstd * gv.w + bv.w);
    *(bf16x4*)(concat + ((size_t)row << 10) + t * 4) = o;
    if (r >= 1024)
        *(bf16x4*)(latln + ((size_t)(bt * 64 + (r - 1024)) << 10) + t * 4) = o;
}

// ---------------------------------------------------------------- qkv8: 256^2 8-phase
// C = A_cat[36864][1024] @ B_cat[.][1024]^T. 8 waves (2M x 4N), per-wave 128x64.
// m201 schedule: per 2 K-tiles 8 phases; each phase {ds_read subtile | stage 1 unit |
// barrier | lgkm0 | 16 MFMA | barrier}; vmcnt(6) only at ph4/ph8 (3 units in flight).
// Stage units (16KB, consumed-set across ALL waves): A0=rows[0,64) both halves (read ph1),
// A1=rows[64,128) (ph3), B0=rows[0,32)u[64,96) (ph1), B1=rows[32,64)u[96,128) (ph2).
// Rotation: ph1:A1(T+1)->b1  ph2:A0(T+2)->b0  ph3:B0(T+2)  ph4:B1(T+2)+vmcnt6
//           ph5:A1(T+2)->b0  ph6:A0(T+3)->b1  ph7:B0(T+3)  ph8:B1(T+3)+vmcnt6
// Swizzle: inverse-swizzled source chunk (c^srow) + XOR ds_read (round-3 pair, 0 conf).
__global__ __launch_bounds__(512) void qkv8(
    const __bf16* __restrict__ A, const __bf16* __restrict__ Bt,
    __bf16* __restrict__ C) {
    __shared__ __bf16 lds[2][2][2][128 * 64];   // [buf][A0/B1][half][row*64+col] 128 KiB
    int tid = threadIdx.x, lane = tid & 63, w = tid >> 6;
    int id = blockIdx.x;
    int swz = (id & 7) * 70 + (id >> 3);        // 560 = 8*70, bijective
    int bm, bn;
    if (swz < 544) { bm = swz >> 2; bn = swz & 3; }                 // kv tiles
    else { int i = swz - 544; bm = 136 + (i >> 1); bn = 4 + (i & 1); }  // q tiles
    int wm = w >> 2, wn = w & 3;
    int l15 = lane & 15, lh = lane >> 4;
    int srow = lane >> 3;
    int scol = ((lane & 7) ^ srow) * 8;         // inverse-swizzled source column
    int browB0 = (w < 4) ? w * 8 : w * 8 + 32;  // B0-unit wave base row (8-aligned)

    int gA0[2], gA1[2], gB0[2], gB1[2];         // per-lane global element offsets
#pragma unroll
    for (int h = 0; h < 2; ++h) {
        gA0[h] = (bm * 256 + h * 128 + w * 8 + srow) * 1024 + scol;
        gA1[h] = gA0[h] + 64 * 1024;
        gB0[h] = (bn * 256 + h * 128 + browB0 + srow) * 1024 + scol;
        gB1[h] = gB0[h] + 32 * 1024;
    }

#define STG_A0(BUF, T)                                                           \
    { gload_lds16(A + (size_t)gA0[0] + (T) * 64, &lds[BUF][0][0][(w * 8) * 64]); \
      gload_lds16(A + (size_t)gA0[1] + (T) * 64, &lds[BUF][0][1][(w * 8) * 64]); }
#define STG_A1(BUF, T)                                                                \
    { gload_lds16(A + (size_t)gA1[0] + (T) * 64, &lds[BUF][0][0][(64 + w * 8) * 64]); \
      gload_lds16(A + (size_t)gA1[1] + (T) * 64, &lds[BUF][0][1][(64 + w * 8) * 64]); }
#define STG_B0(BUF, T)                                                            \
    { gload_lds16(Bt + (size_t)gB0[0] + (T) * 64, &lds[BUF][1][0][browB0 * 64]);  \
      gload_lds16(Bt + (size_t)gB0[1] + (T) * 64, &lds[BUF][1][1][browB0 * 64]); }
#define STG_B1(BUF, T)                                                                  \
    { gload_lds16(Bt + (size_t)gB1[0] + (T) * 64, &lds[BUF][1][0][(browB0 + 32) * 64]); \
      gload_lds16(Bt + (size_t)gB1[1] + (T) * 64, &lds[BUF][1][1][(browB0 + 32) * 64]); }
#define RD_A(BUF, MH, DST)                                                        \
    _Pragma("unroll") for (int mi = 0; mi < 4; ++mi) {                            \
        int row = (MH) * 64 + mi * 16 + l15;                                      \
        const char* base = (const char*)&lds[BUF][0][wm][0];                      \
        _Pragma("unroll") for (int kk = 0; kk < 2; ++kk)                          \
            DST[mi][kk] = *(const bf16x8*)(base + row * 128 +                     \
                                ((kk * 64 + lh * 16) ^ ((row & 7) << 4)));        \
    }
#define RD_B(BUF, NH, DST)                                                        \
    _Pragma("unroll") for (int ni = 0; ni < 2; ++ni) {                            \
        int row = (wn & 1) * 64 + (NH) * 32 + ni * 16 + l15;                      \
        const char* base = (const char*)&lds[BUF][1][wn >> 1][0];                 \
        _Pragma("unroll") for (int kk = 0; kk < 2; ++kk)                          \
            DST[ni][kk] = *(const bf16x8*)(base + row * 128 +                     \
                                ((kk * 64 + lh * 16) ^ ((row & 7) << 4)));        \
    }
#define MM(AF, BF, MH, NH)                                                        \
    __builtin_amdgcn_s_setprio(1);                                                \
    _Pragma("unroll") for (int mi = 0; mi < 4; ++mi)                              \
        _Pragma("unroll") for (int ni = 0; ni < 2; ++ni)                          \
            _Pragma("unroll") for (int kk = 0; kk < 2; ++kk)                      \
                acc[(MH) * 4 + mi][(NH) * 2 + ni] =                               \
                    __builtin_amdgcn_mfma_f32_16x16x32_bf16(                      \
                        AF[mi][kk], BF[ni][kk], acc[(MH) * 4 + mi][(NH) * 2 + ni], 0, 0, 0); \
    __builtin_amdgcn_s_setprio(0);
#define PSYNC                                                                     \
    __builtin_amdgcn_s_barrier();                                                 \
    asm volatile("s_waitcnt lgkmcnt(0)" ::: "memory");                            \
    __builtin_amdgcn_sched_barrier(0);
#define PEND                                                                      \
    __builtin_amdgcn_s_barrier();                                                 \
    __builtin_amdgcn_sched_barrier(0);

    f32x4 acc[8][4] = {};
    bf16x8 Af[4][2], B0f[2][2], B1f[2][2];

    // prologue: tile0 full (buf0) + tile1 {A0,B0,B1} (buf1) = 7 units, 14 loads
    STG_A0(0, 0); STG_A1(0, 0); STG_B0(0, 0); STG_B1(0, 0);
    STG_A0(1, 1); STG_B0(1, 1); STG_B1(1, 1);
    asm volatile("s_waitcnt vmcnt(6)" ::: "memory");   // tile0 resident
    __builtin_amdgcn_s_barrier();
    __builtin_amdgcn_sched_barrier(0);

#pragma unroll 1
    for (int T = 0; T < 16; T += 2) {
        int t2 = (T + 2 < 16) ? T + 2 : T;   // clamped tail: dead units, never read
        int t3 = (T + 3 < 16) ? T + 3 : T;
        // ph1: reads A0,B0 of tile T (buf0); stage A1(T+1)->buf1
        RD_A(0, 0, Af); RD_B(0, 0, B0f);
        STG_A1(1, T + 1);
        PSYNC; MM(Af, B0f, 0, 0); PEND;
        // ph2: read B1 (buf0); stage A0(T+2)->buf0 [A0-unit drained ph1]
        RD_B(0, 1, B1f);
        STG_A0(0, t2);
        PSYNC; MM(Af, B1f, 0, 1); PEND;
        // ph3: read A1 (buf0); stage B0(T+2)->buf0 [B0-unit drained ph1]
        RD_A(0, 1, Af);
        STG_B0(0, t2);
        PSYNC; MM(Af, B0f, 1, 0); PEND;
        // ph4: stage B1(T+2)->buf0 [drained ph2]; vmcnt(6) -> tile T+1 resident
        STG_B1(0, t2);
        asm volatile("s_waitcnt vmcnt(6)" ::: "memory");
        PSYNC; MM(Af, B1f, 1, 1); PEND;
        // ph5: reads A0,B0 of tile T+1 (buf1); stage A1(T+2)->buf0 [drained ph3]
        RD_A(1, 0, Af); RD_B(1, 0, B0f);
        STG_A1(0, t2);
        PSYNC; MM(Af, B0f, 0, 0); PEND;
        // ph6: read B1 (buf1); stage A0(T+3)->buf1 [drained ph5]
        RD_B(1, 1, B1f);
        STG_A0(1, t3);
        PSYNC; MM(Af, B1f, 0, 1); PEND;
        // ph7: read A1 (buf1); stage B0(T+3)->buf1 [drained ph5]
        RD_A(1, 1, Af);
        STG_B0(1, t3);
        PSYNC; MM(Af, B0f, 1, 0); PEND;
        // ph8: stage B1(T+3)->buf1 [drained ph6]; vmcnt(6) -> tile T+2 resident
        STG_B1(1, t3);
        asm volatile("s_waitcnt vmcnt(6)" ::: "memory");
        PSYNC; MM(Af, B1f, 1, 1); PEND;
    }
    asm volatile("s_waitcnt vmcnt(0)" ::: "memory");

    // epilogue: D row = lh*4+jj, col = l15 (m89-verified); q cols fold via bn&3
#pragma unroll
    for (int mf = 0; mf < 8; ++mf)
#pragma unroll
        for (int nf = 0; nf < 4; ++nf)
#pragma unroll
            for (int jj = 0; jj < 4; ++jj) {
                int row = bm * 256 + wm * 128 + mf * 16 + lh * 4 + jj;
                int col = (bn & 3) * 256 + wn * 64 + nf * 16 + l15;
                C[(size_t)row * 1024 + col] = (__bf16)acc[mf][nf][jj];
            }
#undef STG_A0
#undef STG_A1
#undef STG_B0
#undef STG_B1
#undef RD_A
#undef RD_B
#undef MM
#undef PSYNC
#undef PEND
}

// ---------------------------------------------------------------- GEMM 128^2 (m97-style)
#define BKK 64
template <bool OUT_BF16>
__global__ __launch_bounds__(256) void gemm_bf16(
    const __bf16* __restrict__ A, const __bf16* __restrict__ Bt,
    void* __restrict__ C, int M, int N, int K, float scale, int gx) {
    __shared__ __bf16 As[128 * BKK];
    __shared__ __bf16 Bs[128 * BKK];
    int tid  = threadIdx.x;
    int lane = tid & 63, wave = tid >> 6;

    int nwg = gridDim.x;
    int id  = blockIdx.x;
    int cpx = nwg >> 3;
    int swz = (id & 7) * cpx + (id >> 3);
    int bm = swz / gx, bn = swz % gx;

    int wr = (wave >> 1) * 64, wc = (wave & 1) * 64;
    int l15 = lane & 15, lh = lane >> 4;
    int srow = lane >> 3;
    int scol = ((lane & 7) ^ srow) * 8;

    const __bf16* abase[4];
    const __bf16* bbase[4];
#pragma unroll
    for (int i = 0; i < 4; ++i) {
        int r = wave * 32 + i * 8 + srow;
        abase[i] = A + (size_t)(bm * 128 + r) * K + scol;
        bbase[i] = Bt + (size_t)(bn * 128 + r) * K + scol;
    }

    f32x4 acc[4][4] = {};

#pragma unroll 1
    for (int k0 = 0; k0 < K; k0 += BKK) {
        __syncthreads();
#pragma unroll
        for (int i = 0; i < 4; ++i) {
            gload_lds16(abase[i] + k0, &As[(wave * 32 + i * 8) * BKK]);
            gload_lds16(bbase[i] + k0, &Bs[(wave * 32 + i * 8) * BKK]);
        }
        __syncthreads();
#pragma unroll
        for (int kk = 0; kk < BKK; kk += 32) {
            int cb = (kk + lh * 8) * 2;
            bf16x8 af[4], bfr[4];
#pragma unroll
            for (int mi = 0; mi < 4; ++mi) {
                int r = wr + mi * 16 + l15;
                af[mi] = *(const bf16x8*)((const char*)As + r * 128 + (cb ^ ((r & 7) << 4)));
            }
#pragma unroll
            for (int ni = 0; ni < 4; ++ni) {
                int r = wc + ni * 16 + l15;
                bfr[ni] = *(const bf16x8*)((const char*)Bs + r * 128 + (cb ^ ((r & 7) << 4)));
            }
#pragma unroll
            for (int mi = 0; mi < 4; ++mi)
#pragma unroll
                for (int ni = 0; ni < 4; ++ni)
                    acc[mi][ni] = __builtin_amdgcn_mfma_f32_16x16x32_bf16(
                        af[mi], bfr[ni], acc[mi][ni], 0, 0, 0);
        }
    }
#pragma unroll
    for (int mi = 0; mi < 4; ++mi)
#pragma unroll
        for (int ni = 0; ni < 4; ++ni)
#pragma unroll
            for (int jj = 0; jj < 4; ++jj) {
                int row = bm * 128 + wr + mi * 16 + lh * 4 + jj;
                int col = bn * 128 + wc + ni * 16 + l15;
                float val = acc[mi][ni][jj] * scale;
                if (OUT_BF16) ((__bf16*)C)[(size_t)row * N + col] = (__bf16)val;
                else          ((float*)C)[(size_t)row * N + col]  = val;
            }
}

// ---------------------------------------------------------------- attention
__global__ __launch_bounds__(1024) void attn_kernel(
    const __bf16* __restrict__ q,    // rows x 1024-stride, cols [0,512) used
    const __bf16* __restrict__ kv,   // [32][1088][1024]  (k: cols 0..511, v: 512..1023)
    __bf16* __restrict__ o) {        // [32][64][512]
    int blk = blockIdx.x;            // 0..255
    int bt = blk >> 3, h = blk & 7;
    int tid = threadIdx.x;
    int cid  = tid >> 8;
    int ctid = tid & 255;
    int wave = tid >> 6;
    int g    = wave & 3;
    int lane = tid & 63, l15 = lane & 15, lh = lane >> 4;

    __shared__ __bf16 vT[4][64 * 64];
    __shared__ __bf16 Pl[16][16 * 64];
    float* mbuf = (float*)&vT[1][0];
    float* lbuf = mbuf + 256;
    float* Osum = (float*)&Pl[0][0];

    const __bf16* qbase = q + ((size_t)bt * 64 + g * 16) * 1024 + h * 64;
    bf16x8 qf[2];
    qf[0] = *(const bf16x8*)(qbase + (size_t)l15 * 1024 + lh * 8);
    qf[1] = *(const bf16x8*)(qbase + (size_t)l15 * 1024 + 32 + lh * 8);

    const __bf16* kvbt = kv + (size_t)bt * 1088 * 1024;

    float m_s[4], l_s[4];
    f32x4 oacc[4];
#pragma unroll
    for (int jj = 0; jj < 4; ++jj) { m_s[jj] = -1e30f; l_s[jj] = 0.f; }
#pragma unroll
    for (int d = 0; d < 4; ++d) oacc[d] = f32x4{0.f, 0.f, 0.f, 0.f};

    for (int it = 0; it < 5; ++it) {
        int tile = it * 4 + cid;
        bool act = tile < 17;
        int j0 = tile * 64;
        __syncthreads();
        if (act) {
#pragma unroll
            for (int it2 = 0; it2 < 2; ++it2) {
                int idx = it2 * 256 + ctid;
                int j = idx >> 3, c = idx & 7;
                bf16x8 vv = *(const bf16x8*)(kvbt + (size_t)(j0 + j) * 1024 + 512 + h * 64 + c * 8);
#pragma unroll
                for (int e = 0; e < 8; ++e) {
                    int d = c * 8 + e;
                    *(__bf16*)((char*)vT[cid] + d * 128 + ((j * 2) ^ ((d & 7) << 4))) = vv[e];
                }
            }
        }
        __syncthreads();
        if (act) {
            f32x4 s[4];
            f32x4 zero = {0.f, 0.f, 0.f, 0.f};
#pragma unroll
            for (int ni = 0; ni < 4; ++ni) {
                const __bf16* kp = kvbt + (size_t)(j0 + ni * 16 + l15) * 1024 + h * 64;
                bf16x8 kf0 = *(const bf16x8*)(kp + lh * 8);
                bf16x8 kf1 = *(const bf16x8*)(kp + 32 + lh * 8);
                f32x4 t0 = __builtin_amdgcn_mfma_f32_16x16x32_bf16(qf[0], kf0, zero, 0, 0, 0);
                s[ni]    = __builtin_amdgcn_mfma_f32_16x16x32_bf16(qf[1], kf1, t0,   0, 0, 0);
            }
            float tm[4];
#pragma unroll
            for (int jj = 0; jj < 4; ++jj)
                tm[jj] = fmaxf(fmaxf(s[0][jj], s[1][jj]), fmaxf(s[2][jj], s[3][jj]));
#pragma unroll
            for (int m = 1; m < 16; m <<= 1)
#pragma unroll
                for (int jj = 0; jj < 4; ++jj) tm[jj] = fmaxf(tm[jj], __shfl_xor(tm[jj], m));
            float alpha[4];
#pragma unroll
            for (int jj = 0; jj < 4; ++jj) {
                float mn = fmaxf(m_s[jj], tm[jj]);
                alpha[jj] = __expf(m_s[jj] - mn);
                m_s[jj] = mn;
            }
            float p[4][4];
            float ts[4] = {0.f, 0.f, 0.f, 0.f};
#pragma unroll
            for (int ni = 0; ni < 4; ++ni)
#pragma unroll
                for (int jj = 0; jj < 4; ++jj) {
                    p[ni][jj] = __expf(s[ni][jj] - m_s[jj]);
                    ts[jj] += p[ni][jj];
                }
#pragma unroll
            for (int m = 1; m < 16; m <<= 1)
#pragma unroll
                for (int jj = 0; jj < 4; ++jj) ts[jj] += __shfl_xor(ts[jj], m);
#pragma unroll
            for (int jj = 0; jj < 4; ++jj) l_s[jj] = l_s[jj] * alpha[jj] + ts[jj];
#pragma unroll
            for (int d = 0; d < 4; ++d)
#pragma unroll
                for (int jj = 0; jj < 4; ++jj) oacc[d][jj] *= alpha[jj];
#pragma unroll
            for (int ni = 0; ni < 4; ++ni)
#pragma unroll
                for (int jj = 0; jj < 4; ++jj) {
                    int r = lh * 4 + jj, j = ni * 16 + l15;
                    *(__bf16*)((char*)Pl[wave] + r * 128 + ((j * 2) ^ ((r & 7) << 4))) =
                        (__bf16)p[ni][jj];
                }
        }
        __syncthreads();
        if (act) {
            bf16x8 pf[2];
            pf[0] = *(const bf16x8*)((char*)Pl[wave] + l15 * 128 + ((lh * 16)      ^ ((l15 & 7) << 4)));
            pf[1] = *(const bf16x8*)((char*)Pl[wave] + l15 * 128 + ((64 + lh * 16) ^ ((l15 & 7) << 4)));
#pragma unroll
            for (int dblk = 0; dblk < 4; ++dblk) {
                int dr = dblk * 16 + l15;
                bf16x8 vf0 = *(const bf16x8*)((char*)vT[cid] + dr * 128 + ((lh * 16)      ^ ((dr & 7) << 4)));
                bf16x8 vf1 = *(const bf16x8*)((char*)vT[cid] + dr * 128 + ((64 + lh * 16) ^ ((dr & 7) << 4)));
                oacc[dblk] = __builtin_amdgcn_mfma_f32_16x16x32_bf16(pf[0], vf0, oacc[dblk], 0, 0, 0);
                oacc[dblk] = __builtin_amdgcn_mfma_f32_16x16x32_bf16(pf[1], vf1, oacc[dblk], 0, 0, 0);
            }
        }
    }

    __syncthreads();
    if (l15 == 0) {
#pragma unroll
        for (int jj = 0; jj < 4; ++jj) {
            mbuf[(cid * 4 + g) * 16 + lh * 4 + jj] = m_s[jj];
            lbuf[(cid * 4 + g) * 16 + lh * 4 + jj] = l_s[jj];
        }
    }
    __syncthreads();
    float sc[4], Lsum[4];
#pragma unroll
    for (int jj = 0; jj < 4; ++jj) {
        int r = lh * 4 + jj;
        float M = mbuf[(0 * 4 + g) * 16 + r];
#pragma unroll
        for (int c = 1; c < 4; ++c) M = fmaxf(M, mbuf[(c * 4 + g) * 16 + r]);
        sc[jj] = __expf(m_s[jj] - M);
        float L = 0.f;
#pragma unroll
        for (int c = 0; c < 4; ++c)
            L += lbuf[(c * 4 + g) * 16 + r] * __expf(mbuf[(c * 4 + g) * 16 + r] - M);
        Lsum[jj] = L;
    }
#pragma unroll
    for (int c = 0; c < 4; ++c) {
        if (cid == c) {
#pragma unroll
            for (int dblk = 0; dblk < 4; ++dblk)
#pragma unroll
                for (int jj = 0; jj < 4; ++jj) {
                    int off = (g * 16 + lh * 4 + jj) * 64 + dblk * 16 + l15;
                    float v = oacc[dblk][jj] * sc[jj];
                    if (c == 0) Osum[off] = v;
                    else        Osum[off] += v;
                }
        }
        __syncthreads();
    }
    if (cid == 0) {
        __bf16* ob = o + ((size_t)bt * 64 + g * 16) * 512 + h * 64;
#pragma unroll
        for (int dblk = 0; dblk < 4; ++dblk)
#pragma unroll
            for (int jj = 0; jj < 4; ++jj) {
                int r = lh * 4 + jj;
                float v = Osum[(g * 16 + r) * 64 + dblk * 16 + l15] / Lsum[jj];
                ob[(size_t)r * 512 + dblk * 16 + l15] = (__bf16)v;
            }
    }
}

// ---------------------------------------------------------------- launch
extern "C" void kernel_launch(void* const* d_in, const int* in_sizes, int n_in,
                              void* d_out, int out_size, void* d_ws, size_t ws_size,
                              hipStream_t stream) {
    const float* x    = (const float*)d_in[0];
    const float* lat  = (const float*)d_in[1];
    const float* g_m  = (const float*)d_in[2];
    const float* b_m  = (const float*)d_in[3];
    const float* g_l  = (const float*)d_in[4];
    const float* b_l  = (const float*)d_in[5];
    const float* Wq   = (const float*)d_in[6];
    const float* Wkv  = (const float*)d_in[7];
    const float* Wout = (const float*)d_in[8];
    float* out = (float*)d_out;

    char* ws = (char*)d_ws;
    __bf16* A_cat = (__bf16*)ws; ws += (size_t)36864 * 1024 * 2;   // LN(concat) + latln
    __bf16* kvq   = (__bf16*)ws; ws += (size_t)36864 * 1024 * 2;   // kv + q
    __bf16* ab    = (__bf16*)ws; ws += (size_t)2048 * 512 * 2;
    __bf16* B_cat = (__bf16*)ws; ws += (size_t)1536 * 1024 * 2;    // WkvT + WqT
    __bf16* WoutT = (__bf16*)ws; ws += (size_t)1024 * 512 * 2;

    __bf16* latln = A_cat + (size_t)34816 * 1024;
    __bf16* WkvT  = B_cat;
    __bf16* WqT   = B_cat + (size_t)1024 * 1024;
    __bf16* qb    = kvq   + (size_t)34816 * 1024;   // rows 34816+, cols [0,512)

    prep_kernel<<<2048 + 34816, 256, 0, stream>>>(
        Wq, Wkv, Wout, WqT, WkvT, WoutT,
        x, lat, g_m, b_m, g_l, b_l, A_cat, latln);

    // fused 256^2 8-phase: kv (544 tiles) | q (16 tiles); 560 blocks (%8==0)
    qkv8<<<560, 512, 0, stream>>>(A_cat, B_cat, kvq);

    attn_kernel<<<256, 1024, 0, stream>>>(qb, kvq, ab);

    gemm_bf16<false><<<128, 256, 0, stream>>>(ab, WoutT, out, 2048, 1024, 512, 1.0f, 8);
}

// Round 14
// 187.203 us; speedup vs baseline: 1.0098x; 1.0098x over previous
//
#include <hip/hip_runtime.h>
#include <hip/hip_bf16.h>
#include <cstdint>

// B=8 T=4 N1=1024 N2=64 DIM=1024 HEADS=8 DHEAD=64 INNER=512
// BT = 32, NR = N1+N2 = 1088, concat rows = 34816
// Pipeline: {weight transpose | LN} fused -> {kv|q} uniform fused GEMM -> attention
//           -> out GEMM
// R12 configuration (best measured: 186.7 us). Key lessons baked in:
//  - runtime K arg + #pragma unroll 1 keeps GEMM at 80 VGPR (constexpr K -> 96, R11)
//  - fusion via buffer stacking, scalar-only block map (R9's branchy preamble cost 16 VGPR)
//  - inverse-swizzled gload source + XOR ds_read = 0 bank conflicts (R3)
//  - 8-phase/256^2 ports all regressed (R4/R5/R7/R13) -> m97 2-barrier structure kept

typedef __bf16 bf16x8 __attribute__((ext_vector_type(8)));
typedef __bf16 bf16x4 __attribute__((ext_vector_type(4)));
typedef float  f32x4  __attribute__((ext_vector_type(4)));

__device__ __forceinline__ void gload_lds16(const void* g, void* l) {
    __builtin_amdgcn_global_load_lds(
        (const __attribute__((address_space(1))) unsigned int*)g,
        (__attribute__((address_space(3))) unsigned int*)l, 16, 0, 0);
}

// ---------------------------------------------------------------- prep: transpose + LN
__global__ __launch_bounds__(256) void prep_kernel(
    const float* __restrict__ Wq, const float* __restrict__ Wkv,
    const float* __restrict__ Wout,
    __bf16* __restrict__ WqT, __bf16* __restrict__ WkvT, __bf16* __restrict__ WoutT,
    const float* __restrict__ x, const float* __restrict__ lat,
    const float* __restrict__ g_m, const float* __restrict__ b_m,
    const float* __restrict__ g_l, const float* __restrict__ b_l,
    __bf16* __restrict__ concat, __bf16* __restrict__ latln) {
    __shared__ float tile[32][33];
    __shared__ float ss[4], qq[4];
    int id = blockIdx.x;
    if (id < 2048) {
        const float* src; __bf16* dst; int N; int bx, by; float wscale;
        if (id < 512)       { src = Wq;   dst = WqT;   N = 512;
                              bx = id & 15;  by = id >> 4;  wscale = 0.125f; }
        else if (id < 1536) { int i = id - 512;  src = Wkv;  dst = WkvT;  N = 1024;
                              bx = i & 31;  by = i >> 5;  wscale = 1.0f; }
        else                { int i = id - 1536; src = Wout; dst = WoutT; N = 1024;
                              bx = i & 31;  by = i >> 5;  wscale = 1.0f; }
        int K = (id < 1536) ? 1024 : 512;
        int n0 = bx * 32, k0 = by * 32;
        int tx = threadIdx.x & 31, ty = threadIdx.x >> 5;   // 32x8
#pragma unroll
        for (int i = 0; i < 4; ++i)
            tile[ty + i * 8][tx] = src[(size_t)(k0 + ty + i * 8) * N + n0 + tx];
        __syncthreads();
#pragma unroll
        for (int i = 0; i < 4; ++i)
            dst[(size_t)(n0 + ty + i * 8) * K + k0 + tx] =
                (__bf16)(tile[tx][ty + i * 8] * wscale);
        return;
    }
    // ---------- layernorm ----------
    int row = id - 2048;                // 0..34815
    int bt  = row / 1088;
    int r   = row - bt * 1088;
    const float *src, *g, *b;
    if (r < 1024) { src = x   + ((size_t)(bt * 1024 + r) << 10);        g = g_m; b = b_m; }
    else          { src = lat + ((size_t)(bt * 64 + (r - 1024)) << 10); g = g_l; b = b_l; }
    int t = threadIdx.x;
    float4 v = ((const float4*)src)[t];
    float s = v.x + v.y + v.z + v.w;
    float q = v.x * v.x + v.y * v.y + v.z * v.z + v.w * v.w;
#pragma unroll
    for (int m = 1; m < 64; m <<= 1) { s += __shfl_xor(s, m); q += __shfl_xor(q, m); }
    int w = t >> 6;
    if ((t & 63) == 0) { ss[w] = s; qq[w] = q; }
    __syncthreads();
    s = ss[0] + ss[1] + ss[2] + ss[3];
    q = qq[0] + qq[1] + qq[2] + qq[3];
    float mean = s * (1.0f / 1024.0f);
    float var  = q * (1.0f / 1024.0f) - mean * mean;
    float rstd = rsqrtf(var + 1e-5f);
    float4 gv = ((const float4*)g)[t];
    float4 bv = ((const float4*)b)[t];
    bf16x4 o;
    o[0] = (__bf16)((v.x - mean) * rstd * gv.x + bv.x);
    o[1] = (__bf16)((v.y - mean) * rstd * gv.y + bv.y);
    o[2] = (__bf16)((v.z - mean) * rstd * gv.z + bv.z);
    o[3] = (__bf16)((v.w - mean) * rstd * gv.w + bv.w);
    *(bf16x4*)(concat + ((size_t)row << 10) + t * 4) = o;
    if (r >= 1024)
        *(bf16x4*)(latln + ((size_t)(bt * 64 + (r - 1024)) << 10) + t * 4) = o;
}

// ---------------------------------------------------------------- uniform fused {kv|q}
// C[.][1024] = A_cat rows @ B_cat rows^T. 128x128 tile, BK=64, 4 waves, runtime K.
// Blocks [0,2176): kv tiles (bm<272, bn<8). Blocks [2176,2240): q tiles
// (bm=272..287, bn=8..11; C col = (bn&7)*128 -> [0,512)). Body is block-uniform.
#define BKK 64

__global__ __launch_bounds__(256) void qkv_gemm(
    const __bf16* __restrict__ A, const __bf16* __restrict__ Bt,
    __bf16* __restrict__ C, int K) {
    __shared__ __bf16 As[128 * BKK];
    __shared__ __bf16 Bs[128 * BKK];
    int tid  = threadIdx.x;
    int lane = tid & 63, wave = tid >> 6;
    int id = blockIdx.x;

    int bm, bn;                      // scalar-only divergence
    if (id < 2176) {
        int swz = (id & 7) * 272 + (id >> 3);
        bm = swz >> 3; bn = swz & 7;
    } else {
        int i2 = id - 2176;
        int swz = (i2 & 7) * 8 + (i2 >> 3);
        bm = 272 + (swz >> 2); bn = 8 + (swz & 3);
    }

    int wr = (wave >> 1) * 64, wc = (wave & 1) * 64;
    int l15 = lane & 15, lh = lane >> 4;
    int srow = lane >> 3;
    int scol = ((lane & 7) ^ srow) * 8;           // inverse-swizzled source column

    const __bf16* abase[4];
    const __bf16* bbase[4];
#pragma unroll
    for (int i = 0; i < 4; ++i) {
        int r = wave * 32 + i * 8 + srow;
        abase[i] = A  + (size_t)(bm * 128 + r) * K + scol;
        bbase[i] = Bt + (size_t)(bn * 128 + r) * K + scol;
    }

    f32x4 acc[4][4] = {};

#pragma unroll 1
    for (int k0 = 0; k0 < K; k0 += BKK) {
        __syncthreads();
#pragma unroll
        for (int i = 0; i < 4; ++i) {
            gload_lds16(abase[i] + k0, &As[(wave * 32 + i * 8) * BKK]);
            gload_lds16(bbase[i] + k0, &Bs[(wave * 32 + i * 8) * BKK]);
        }
        __syncthreads();
#pragma unroll
        for (int kk = 0; kk < BKK; kk += 32) {
            int cb = (kk + lh * 8) * 2;
            bf16x8 af[4], bfr[4];
#pragma unroll
            for (int mi = 0; mi < 4; ++mi) {
                int r = wr + mi * 16 + l15;
                af[mi] = *(const bf16x8*)((const char*)As + r * 128 + (cb ^ ((r & 7) << 4)));
            }
#pragma unroll
            for (int ni = 0; ni < 4; ++ni) {
                int r = wc + ni * 16 + l15;
                bfr[ni] = *(const bf16x8*)((const char*)Bs + r * 128 + (cb ^ ((r & 7) << 4)));
            }
#pragma unroll
            for (int mi = 0; mi < 4; ++mi)
#pragma unroll
                for (int ni = 0; ni < 4; ++ni)
                    acc[mi][ni] = __builtin_amdgcn_mfma_f32_16x16x32_bf16(
                        af[mi], bfr[ni], acc[mi][ni], 0, 0, 0);
        }
    }
    // epilogue: D row = lh*4+jj, col = l15 (m89-verified). q cols fold via bn&7.
#pragma unroll
    for (int mi = 0; mi < 4; ++mi)
#pragma unroll
        for (int ni = 0; ni < 4; ++ni)
#pragma unroll
            for (int jj = 0; jj < 4; ++jj) {
                int row = bm * 128 + wr + mi * 16 + lh * 4 + jj;
                int col = (bn & 7) * 128 + wc + ni * 16 + l15;
                C[(size_t)row * 1024 + col] = (__bf16)acc[mi][ni][jj];
            }
}

// ---------------------------------------------------------------- GEMM 128^2 (m97-style)
template <bool OUT_BF16>
__global__ __launch_bounds__(256) void gemm_bf16(
    const __bf16* __restrict__ A, const __bf16* __restrict__ Bt,
    void* __restrict__ C, int M, int N, int K, float scale, int gx) {
    __shared__ __bf16 As[128 * BKK];
    __shared__ __bf16 Bs[128 * BKK];
    int tid  = threadIdx.x;
    int lane = tid & 63, wave = tid >> 6;

    int nwg = gridDim.x;
    int id  = blockIdx.x;
    int cpx = nwg >> 3;
    int swz = (id & 7) * cpx + (id >> 3);
    int bm = swz / gx, bn = swz % gx;

    int wr = (wave >> 1) * 64, wc = (wave & 1) * 64;
    int l15 = lane & 15, lh = lane >> 4;
    int srow = lane >> 3;
    int scol = ((lane & 7) ^ srow) * 8;           // inverse-swizzled source column

    const __bf16* abase[4];
    const __bf16* bbase[4];
#pragma unroll
    for (int i = 0; i < 4; ++i) {
        int r = wave * 32 + i * 8 + srow;
        abase[i] = A + (size_t)(bm * 128 + r) * K + scol;
        bbase[i] = Bt + (size_t)(bn * 128 + r) * K + scol;
    }

    f32x4 acc[4][4] = {};

#pragma unroll 1
    for (int k0 = 0; k0 < K; k0 += BKK) {
        __syncthreads();
#pragma unroll
        for (int i = 0; i < 4; ++i) {
            gload_lds16(abase[i] + k0, &As[(wave * 32 + i * 8) * BKK]);
            gload_lds16(bbase[i] + k0, &Bs[(wave * 32 + i * 8) * BKK]);
        }
        __syncthreads();
#pragma unroll
        for (int kk = 0; kk < BKK; kk += 32) {
            int cb = (kk + lh * 8) * 2;
            bf16x8 af[4], bfr[4];
#pragma unroll
            for (int mi = 0; mi < 4; ++mi) {
                int r = wr + mi * 16 + l15;
                af[mi] = *(const bf16x8*)((const char*)As + r * 128 + (cb ^ ((r & 7) << 4)));
            }
#pragma unroll
            for (int ni = 0; ni < 4; ++ni) {
                int r = wc + ni * 16 + l15;
                bfr[ni] = *(const bf16x8*)((const char*)Bs + r * 128 + (cb ^ ((r & 7) << 4)));
            }
#pragma unroll
            for (int mi = 0; mi < 4; ++mi)
#pragma unroll
                for (int ni = 0; ni < 4; ++ni)
                    acc[mi][ni] = __builtin_amdgcn_mfma_f32_16x16x32_bf16(
                        af[mi], bfr[ni], acc[mi][ni], 0, 0, 0);
        }
    }
#pragma unroll
    for (int mi = 0; mi < 4; ++mi)
#pragma unroll
        for (int ni = 0; ni < 4; ++ni)
#pragma unroll
            for (int jj = 0; jj < 4; ++jj) {
                int row = bm * 128 + wr + mi * 16 + lh * 4 + jj;
                int col = bn * 128 + wc + ni * 16 + l15;
                float val = acc[mi][ni][jj] * scale;
                if (OUT_BF16) ((__bf16*)C)[(size_t)row * N + col] = (__bf16)val;
                else          ((float*)C)[(size_t)row * N + col]  = val;
            }
}

// ---------------------------------------------------------------- attention
__global__ __launch_bounds__(1024) void attn_kernel(
    const __bf16* __restrict__ q,    // rows x 1024-stride, cols [0,512) used
    const __bf16* __restrict__ kv,   // [32][1088][1024]  (k: cols 0..511, v: 512..1023)
    __bf16* __restrict__ o) {        // [32][64][512]
    int blk = blockIdx.x;            // 0..255
    int bt = blk >> 3, h = blk & 7;
    int tid = threadIdx.x;
    int cid  = tid >> 8;             // KV chunk 0..3
    int ctid = tid & 255;
    int wave = tid >> 6;             // 0..15
    int g    = wave & 3;             // q-row group
    int lane = tid & 63, l15 = lane & 15, lh = lane >> 4;

    __shared__ __bf16 vT[4][64 * 64];     // per-chunk [d][j] swizzled, 32 KB
    __shared__ __bf16 Pl[16][16 * 64];    // per-wave  [r][j] swizzled, 32 KB
    float* mbuf = (float*)&vT[1][0];      // [4][4][16]  (aliased, dead region)
    float* lbuf = mbuf + 256;             // [4][4][16]
    float* Osum = (float*)&Pl[0][0];      // [4][16][64]

    const __bf16* qbase = q + ((size_t)bt * 64 + g * 16) * 1024 + h * 64;
    bf16x8 qf[2];
    qf[0] = *(const bf16x8*)(qbase + (size_t)l15 * 1024 + lh * 8);
    qf[1] = *(const bf16x8*)(qbase + (size_t)l15 * 1024 + 32 + lh * 8);

    const __bf16* kvbt = kv + (size_t)bt * 1088 * 1024;

    float m_s[4], l_s[4];
    f32x4 oacc[4];
#pragma unroll
    for (int jj = 0; jj < 4; ++jj) { m_s[jj] = -1e30f; l_s[jj] = 0.f; }
#pragma unroll
    for (int d = 0; d < 4; ++d) oacc[d] = f32x4{0.f, 0.f, 0.f, 0.f};

    for (int it = 0; it < 5; ++it) {
        int tile = it * 4 + cid;
        bool act = tile < 17;
        int j0 = tile * 64;
        __syncthreads();
        if (act) {
#pragma unroll
            for (int it2 = 0; it2 < 2; ++it2) {
                int idx = it2 * 256 + ctid;
                int j = idx >> 3, c = idx & 7;
                bf16x8 vv = *(const bf16x8*)(kvbt + (size_t)(j0 + j) * 1024 + 512 + h * 64 + c * 8);
#pragma unroll
                for (int e = 0; e < 8; ++e) {
                    int d = c * 8 + e;
                    *(__bf16*)((char*)vT[cid] + d * 128 + ((j * 2) ^ ((d & 7) << 4))) = vv[e];
                }
            }
        }
        __syncthreads();
        if (act) {
            f32x4 s[4];
            f32x4 zero = {0.f, 0.f, 0.f, 0.f};
#pragma unroll
            for (int ni = 0; ni < 4; ++ni) {
                const __bf16* kp = kvbt + (size_t)(j0 + ni * 16 + l15) * 1024 + h * 64;
                bf16x8 kf0 = *(const bf16x8*)(kp + lh * 8);
                bf16x8 kf1 = *(const bf16x8*)(kp + 32 + lh * 8);
                f32x4 t0 = __builtin_amdgcn_mfma_f32_16x16x32_bf16(qf[0], kf0, zero, 0, 0, 0);
                s[ni]    = __builtin_amdgcn_mfma_f32_16x16x32_bf16(qf[1], kf1, t0,   0, 0, 0);
            }
            float tm[4];
#pragma unroll
            for (int jj = 0; jj < 4; ++jj)
                tm[jj] = fmaxf(fmaxf(s[0][jj], s[1][jj]), fmaxf(s[2][jj], s[3][jj]));
#pragma unroll
            for (int m = 1; m < 16; m <<= 1)
#pragma unroll
                for (int jj = 0; jj < 4; ++jj) tm[jj] = fmaxf(tm[jj], __shfl_xor(tm[jj], m));
            float alpha[4];
#pragma unroll
            for (int jj = 0; jj < 4; ++jj) {
                float mn = fmaxf(m_s[jj], tm[jj]);
                alpha[jj] = __expf(m_s[jj] - mn);
                m_s[jj] = mn;
            }
            float p[4][4];
            float ts[4] = {0.f, 0.f, 0.f, 0.f};
#pragma unroll
            for (int ni = 0; ni < 4; ++ni)
#pragma unroll
                for (int jj = 0; jj < 4; ++jj) {
                    p[ni][jj] = __expf(s[ni][jj] - m_s[jj]);
                    ts[jj] += p[ni][jj];
                }
#pragma unroll
            for (int m = 1; m < 16; m <<= 1)
#pragma unroll
                for (int jj = 0; jj < 4; ++jj) ts[jj] += __shfl_xor(ts[jj], m);
#pragma unroll
            for (int jj = 0; jj < 4; ++jj) l_s[jj] = l_s[jj] * alpha[jj] + ts[jj];
#pragma unroll
            for (int d = 0; d < 4; ++d)
#pragma unroll
                for (int jj = 0; jj < 4; ++jj) oacc[d][jj] *= alpha[jj];
#pragma unroll
            for (int ni = 0; ni < 4; ++ni)
#pragma unroll
                for (int jj = 0; jj < 4; ++jj) {
                    int r = lh * 4 + jj, j = ni * 16 + l15;
                    *(__bf16*)((char*)Pl[wave] + r * 128 + ((j * 2) ^ ((r & 7) << 4))) =
                        (__bf16)p[ni][jj];
                }
        }
        __syncthreads();   // P write -> P read
        if (act) {
            bf16x8 pf[2];
            pf[0] = *(const bf16x8*)((char*)Pl[wave] + l15 * 128 + ((lh * 16)      ^ ((l15 & 7) << 4)));
            pf[1] = *(const bf16x8*)((char*)Pl[wave] + l15 * 128 + ((64 + lh * 16) ^ ((l15 & 7) << 4)));
#pragma unroll
            for (int dblk = 0; dblk < 4; ++dblk) {
                int dr = dblk * 16 + l15;
                bf16x8 vf0 = *(const bf16x8*)((char*)vT[cid] + dr * 128 + ((lh * 16)      ^ ((dr & 7) << 4)));
                bf16x8 vf1 = *(const bf16x8*)((char*)vT[cid] + dr * 128 + ((64 + lh * 16) ^ ((dr & 7) << 4)));
                oacc[dblk] = __builtin_amdgcn_mfma_f32_16x16x32_bf16(pf[0], vf0, oacc[dblk], 0, 0, 0);
                oacc[dblk] = __builtin_amdgcn_mfma_f32_16x16x32_bf16(pf[1], vf1, oacc[dblk], 0, 0, 0);
            }
        }
    }

    // -------- flash merge of 4 chunk-partials --------
    __syncthreads();
    if (l15 == 0) {
#pragma unroll
        for (int jj = 0; jj < 4; ++jj) {
            mbuf[(cid * 4 + g) * 16 + lh * 4 + jj] = m_s[jj];
            lbuf[(cid * 4 + g) * 16 + lh * 4 + jj] = l_s[jj];
        }
    }
    __syncthreads();
    float sc[4], Lsum[4];
#pragma unroll
    for (int jj = 0; jj < 4; ++jj) {
        int r = lh * 4 + jj;
        float M = mbuf[(0 * 4 + g) * 16 + r];
#pragma unroll
        for (int c = 1; c < 4; ++c) M = fmaxf(M, mbuf[(c * 4 + g) * 16 + r]);
        sc[jj] = __expf(m_s[jj] - M);
        float L = 0.f;
#pragma unroll
        for (int c = 0; c < 4; ++c)
            L += lbuf[(c * 4 + g) * 16 + r] * __expf(mbuf[(c * 4 + g) * 16 + r] - M);
        Lsum[jj] = L;
    }
#pragma unroll
    for (int c = 0; c < 4; ++c) {
        if (cid == c) {
#pragma unroll
            for (int dblk = 0; dblk < 4; ++dblk)
#pragma unroll
                for (int jj = 0; jj < 4; ++jj) {
                    int off = (g * 16 + lh * 4 + jj) * 64 + dblk * 16 + l15;
                    float v = oacc[dblk][jj] * sc[jj];
                    if (c == 0) Osum[off] = v;
                    else        Osum[off] += v;
                }
        }
        __syncthreads();
    }
    if (cid == 0) {
        __bf16* ob = o + ((size_t)bt * 64 + g * 16) * 512 + h * 64;
#pragma unroll
        for (int dblk = 0; dblk < 4; ++dblk)
#pragma unroll
            for (int jj = 0; jj < 4; ++jj) {
                int r = lh * 4 + jj;
                float v = Osum[(g * 16 + r) * 64 + dblk * 16 + l15] / Lsum[jj];
                ob[(size_t)r * 512 + dblk * 16 + l15] = (__bf16)v;
            }
    }
}

// ---------------------------------------------------------------- launch
extern "C" void kernel_launch(void* const* d_in, const int* in_sizes, int n_in,
                              void* d_out, int out_size, void* d_ws, size_t ws_size,
                              hipStream_t stream) {
    const float* x    = (const float*)d_in[0];
    const float* lat  = (const float*)d_in[1];
    const float* g_m  = (const float*)d_in[2];
    const float* b_m  = (const float*)d_in[3];
    const float* g_l  = (const float*)d_in[4];
    const float* b_l  = (const float*)d_in[5];
    const float* Wq   = (const float*)d_in[6];
    const float* Wkv  = (const float*)d_in[7];
    const float* Wout = (const float*)d_in[8];
    float* out = (float*)d_out;

    char* ws = (char*)d_ws;
    __bf16* A_cat = (__bf16*)ws; ws += (size_t)36864 * 1024 * 2;   // LN(concat) + latln
    __bf16* kvq   = (__bf16*)ws; ws += (size_t)36864 * 1024 * 2;   // kv + q
    __bf16* ab    = (__bf16*)ws; ws += (size_t)2048 * 512 * 2;
    __bf16* B_cat = (__bf16*)ws; ws += (size_t)1536 * 1024 * 2;    // WkvT + WqT
    __bf16* WoutT = (__bf16*)ws; ws += (size_t)1024 * 512 * 2;

    __bf16* latln = A_cat + (size_t)34816 * 1024;
    __bf16* WkvT  = B_cat;
    __bf16* WqT   = B_cat + (size_t)1024 * 1024;
    __bf16* qb    = kvq   + (size_t)34816 * 1024;   // rows 34816+, cols [0,512)

    // fused: weight transposes (2048 blocks) | LN (34816 blocks)
    prep_kernel<<<2048 + 34816, 256, 0, stream>>>(
        Wq, Wkv, Wout, WqT, WkvT, WoutT,
        x, lat, g_m, b_m, g_l, b_l, A_cat, latln);

    // uniform fused: kv (2176 blocks) | q (64 blocks, overlapped in tail); runtime K
    qkv_gemm<<<2240, 256, 0, stream>>>(A_cat, B_cat, kvq, 1024);

    attn_kernel<<<256, 1024, 0, stream>>>(qb, kvq, ab);

    // out = attn @ Wout   (M=2048, N=1024, K=512); nwg = 16*8 = 128
    gemm_bf16<false><<<128, 256, 0, stream>>>(ab, WoutT, out, 2048, 1024, 512, 1.0f, 8);
}